// Round 9
// baseline (281.207 us; speedup 1.0000x reference)
//
#include <hip/hip_runtime.h>

#define N_NODES 50000
#define N_EDGES 800000
#define F_IN    128
#define HID     32
#define HEADS   4
#define OUT_C   16

#define NBKT 196      // buckets = dst>>8 ; 196*256 = 50176 >= N_NODES
#define CAP  5120     // per-bucket capacity; mean 4082
#define EPB  4096     // edges per bucketA block; 196 blocks cover 802816
#define NB64 782      // ceil(N_NODES/64)
#define PB   12500    // gather blocks per pass: 12500*4 = 50000 nodes exactly

// bf16 helpers (RNE)
__device__ __forceinline__ unsigned short f2bf(float f) {
    unsigned int u = __float_as_uint(f);
    u += 0x7FFFu + ((u >> 16) & 1u);
    return (unsigned short)(u >> 16);
}
__device__ __forceinline__ float bf_lo(unsigned int u) { return __uint_as_float(u << 16); }
__device__ __forceinline__ float bf_hi(unsigned int u) { return __uint_as_float(u & 0xFFFF0000u); }

__device__ __forceinline__ float edge_w(float asv, float adv) {
    float v = asv + adv;
    v = (v > 0.f) ? v : 0.2f * v;        // leaky_relu(0.2)
    return __expf(v);                    // softmax shift-invariant; logits O(1)
}

// ================================================================ F1 = k_emb (h0 = x@Wemb+bemb) ∪ bucketA
__global__ __launch_bounds__(256) void k_F1(const float* __restrict__ x,
                                            const float* __restrict__ Wemb,
                                            const float* __restrict__ bemb,
                                            float* __restrict__ h0,
                                            const int* __restrict__ ei,
                                            int* __restrict__ gcnt,
                                            unsigned int* __restrict__ pairs,
                                            int* __restrict__ esrc) {
    __shared__ float xs[64][132];
    __shared__ float Wl[F_IN][HID];
    __shared__ float bl[HID];
    __shared__ int hist[NBKT];
    __shared__ int base[NBKT];
    int t = threadIdx.x;
    if (blockIdx.x < NB64) {
        int node0 = blockIdx.x * 64;
        if (t < HID) bl[t] = bemb[t];
        #pragma unroll
        for (int it = 0; it < 4; it++) {
            int idx = it * 256 + t;
            *(float4*)((float*)Wl + idx * 4) = *(const float4*)(Wemb + idx * 4);
        }
        #pragma unroll
        for (int it = 0; it < 8; it++) {
            int idx = it * 256 + t;
            int row = idx >> 5, c4 = idx & 31;
            float4 v = make_float4(0.f, 0.f, 0.f, 0.f);
            if (node0 + row < N_NODES) v = *(const float4*)(x + (size_t)(node0 + row) * F_IN + c4 * 4);
            *(float4*)&xs[row][c4 * 4] = v;
        }
        __syncthreads();
        int c = t & 7, g = t >> 3;
        float acc[2][4] = {};
        for (int k = 0; k < F_IN; k++) {
            float4 w4 = *(const float4*)&Wl[k][c * 4];
            #pragma unroll
            for (int n = 0; n < 2; n++) {
                float xv = xs[g * 2 + n][k];
                acc[n][0] += xv * w4.x; acc[n][1] += xv * w4.y;
                acc[n][2] += xv * w4.z; acc[n][3] += xv * w4.w;
            }
        }
        #pragma unroll
        for (int n = 0; n < 2; n++) {
            int node = node0 + g * 2 + n;
            if (node < N_NODES) {
                float4 o = make_float4(acc[n][0] + bl[c * 4], acc[n][1] + bl[c * 4 + 1],
                                       acc[n][2] + bl[c * 4 + 2], acc[n][3] + bl[c * 4 + 3]);
                *(float4*)(h0 + (size_t)node * HID + c * 4) = o;
            }
        }
    } else {
        if (blockIdx.x == NB64 && t < 16) esrc[N_EDGES + t] = 0;   // pad: lets gathers drop the idx clamp
        int e0 = (blockIdx.x - NB64) * EPB;
        for (int i = t; i < NBKT; i += 256) hist[i] = 0;
        __syncthreads();
        unsigned int p[16];
        int bb[16];
        #pragma unroll
        for (int i = 0; i < 16; i++) {
            int e = e0 + i * 256 + t;
            bb[i] = -1;
            if (e < N_EDGES) {
                int s = ei[e], d = ei[N_EDGES + e];
                p[i] = ((unsigned int)s << 8) | (unsigned int)(d & 255);
                bb[i] = d >> 8;
                atomicAdd(&hist[bb[i]], 1);
            }
        }
        __syncthreads();
        for (int i = t; i < NBKT; i += 256) {
            int c = hist[i];
            base[i] = i * CAP + (c ? atomicAdd(&gcnt[i], c) : 0);
            hist[i] = 0;
        }
        __syncthreads();
        #pragma unroll
        for (int i = 0; i < 16; i++) {
            if (bb[i] >= 0) {
                int off = atomicAdd(&hist[bb[i]], 1);
                pairs[base[bb[i]] + off] = p[i];
            }
        }
    }
}

// ================================================================ F2 = h1f (head-major bf16 h1 + alpha dots [H][N]) ∪ bucketB
__global__ __launch_bounds__(256) void k_F2(const float* __restrict__ h0,
                                            const float* __restrict__ W1,
                                            const float* __restrict__ a_src,
                                            const float* __restrict__ a_dst,
                                            unsigned short* __restrict__ h1,   // [4][N][32] bf16
                                            float* __restrict__ as, float* __restrict__ ad,  // [4][N]
                                            const unsigned int* __restrict__ pairs,
                                            const int* __restrict__ gcnt,
                                            int* __restrict__ rowptr,
                                            int* __restrict__ esrc) {
    __shared__ float xs[64][36];
    __shared__ float Wl[HID][128];
    __shared__ int cnt[256];
    __shared__ int cur[256];
    __shared__ int wsum[4];
    int t = threadIdx.x;
    if (blockIdx.x < NB64) {
        int node0 = blockIdx.x * 64;
        #pragma unroll
        for (int it = 0; it < 4; it++) {
            int idx = it * 256 + t;
            *(float4*)((float*)Wl + idx * 4) = *(const float4*)(W1 + idx * 4);
        }
        #pragma unroll
        for (int it = 0; it < 2; it++) {
            int idx = it * 256 + t;
            int row = idx >> 3, c4 = idx & 7;
            float4 v = make_float4(0.f, 0.f, 0.f, 0.f);
            if (node0 + row < N_NODES) v = *(const float4*)(h0 + (size_t)(node0 + row) * HID + c4 * 4);
            *(float4*)&xs[row][c4 * 4] = v;
        }
        __syncthreads();
        int c = t & 31, g = t >> 5;
        float acc[8][4] = {};
        for (int k = 0; k < HID; k++) {
            float4 w4 = *(const float4*)&Wl[k][c * 4];
            #pragma unroll
            for (int n = 0; n < 8; n++) {
                float xv = xs[g * 8 + n][k];
                acc[n][0] += xv * w4.x; acc[n][1] += xv * w4.y;
                acc[n][2] += xv * w4.z; acc[n][3] += xv * w4.w;
            }
        }
        float4 av = *(const float4*)(a_src + c * 4);
        float4 dv = *(const float4*)(a_dst + c * 4);
        float ps[8], pd[8];
        #pragma unroll
        for (int n = 0; n < 8; n++) {
            int node = node0 + g * 8 + n;
            if (node < N_NODES) {
                ushort4 o;
                o.x = f2bf(acc[n][0]); o.y = f2bf(acc[n][1]);
                o.z = f2bf(acc[n][2]); o.w = f2bf(acc[n][3]);
                *(ushort4*)(h1 + ((size_t)(c >> 3) * N_NODES + node) * 32 + (c & 7) * 4) = o;
            }
            ps[n] = acc[n][0] * av.x + acc[n][1] * av.y + acc[n][2] * av.z + acc[n][3] * av.w;
            pd[n] = acc[n][0] * dv.x + acc[n][1] * dv.y + acc[n][2] * dv.z + acc[n][3] * dv.w;
        }
        #pragma unroll
        for (int mask = 1; mask <= 4; mask <<= 1) {
            #pragma unroll
            for (int n = 0; n < 8; n++) {
                ps[n] += __shfl_xor(ps[n], mask, 64);
                pd[n] += __shfl_xor(pd[n], mask, 64);
            }
        }
        if ((c & 7) == 0) {
            int hh = c >> 3;
            #pragma unroll
            for (int n = 0; n < 8; n++) {
                int node = node0 + g * 8 + n;
                if (node < N_NODES) {
                    as[(size_t)hh * N_NODES + node] = ps[n];
                    ad[(size_t)hh * N_NODES + node] = pd[n];
                }
            }
        }
    } else {
        int b = blockIdx.x - NB64;
        int lane = t & 63, wv = t >> 6;
        int v0 = (t < NBKT && t < b) ? gcnt[t] : 0;
        #pragma unroll
        for (int mask = 1; mask < 64; mask <<= 1) v0 += __shfl_xor(v0, mask, 64);
        if (lane == 0) wsum[wv] = v0;
        __syncthreads();
        int base = wsum[0] + wsum[1] + wsum[2] + wsum[3];
        int n0 = b << 8;
        int cntb = gcnt[b];
        int s0 = b * CAP;
        cnt[t] = 0;
        __syncthreads();
        for (int i = t; i < cntb; i += 256) atomicAdd(&cnt[pairs[s0 + i] & 255], 1);
        __syncthreads();
        int v = cnt[t], x = v;
        #pragma unroll
        for (int off = 1; off < 64; off <<= 1) { int y = __shfl_up(x, off, 64); if (lane >= off) x += y; }
        __syncthreads();
        if (lane == 63) wsum[wv] = x;
        __syncthreads();
        int add = 0;
        for (int j = 0; j < wv; j++) add += wsum[j];
        int excl = base + (x - v) + add;
        cur[t] = excl;
        if (n0 + t < N_NODES) rowptr[n0 + t] = excl;
        if (b == 0 && t == 0) rowptr[N_NODES] = N_EDGES;
        __syncthreads();
        for (int i = t; i < cntb; i += 256) {
            unsigned int p = pairs[s0 + i];
            int pos = atomicAdd(&cur[p & 255], 1);
            esrc[pos] = (int)(p >> 8);
        }
    }
}

// ================================================================ h2 = out1(bf16) @ W2, head-pair-major bf16 h2 + alpha2 [H][N]
__global__ __launch_bounds__(256) void k_h2f(const unsigned int* __restrict__ hin,  // [N][64] bf16x2
                                             const float* __restrict__ W2,
                                             const float* __restrict__ a_src,
                                             const float* __restrict__ a_dst,
                                             unsigned short* __restrict__ h2,       // [2][N][32] bf16
                                             float* __restrict__ as, float* __restrict__ ad) {  // [4][N]
    __shared__ float xs[64][132];
    __shared__ float Wl[128][64];
    int t = threadIdx.x;
    int node0 = blockIdx.x * 64;
    #pragma unroll
    for (int it = 0; it < 8; it++) {
        int idx = it * 256 + t;
        *(float4*)((float*)Wl + idx * 4) = *(const float4*)(W2 + idx * 4);
    }
    #pragma unroll
    for (int it = 0; it < 8; it++) {
        int idx = it * 256 + t;
        int row = idx >> 5, c4 = idx & 31;
        float4 v = make_float4(0.f, 0.f, 0.f, 0.f);
        if (node0 + row < N_NODES) {
            uint2 u = *(const uint2*)(hin + (size_t)(node0 + row) * 64 + c4 * 2);
            v = make_float4(bf_lo(u.x), bf_hi(u.x), bf_lo(u.y), bf_hi(u.y));
        }
        *(float4*)&xs[row][c4 * 4] = v;
    }
    __syncthreads();
    int c = t & 15, g = t >> 4;
    float acc[4][4] = {};
    for (int k = 0; k < 128; k++) {
        float4 w4 = *(const float4*)&Wl[k][c * 4];
        #pragma unroll
        for (int n = 0; n < 4; n++) {
            float xv = xs[g * 4 + n][k];
            acc[n][0] += xv * w4.x; acc[n][1] += xv * w4.y;
            acc[n][2] += xv * w4.z; acc[n][3] += xv * w4.w;
        }
    }
    float4 av = *(const float4*)(a_src + c * 4);
    float4 dv = *(const float4*)(a_dst + c * 4);
    float ps[4], pd[4];
    #pragma unroll
    for (int n = 0; n < 4; n++) {
        int node = node0 + g * 4 + n;
        if (node < N_NODES) {
            ushort4 o;
            o.x = f2bf(acc[n][0]); o.y = f2bf(acc[n][1]);
            o.z = f2bf(acc[n][2]); o.w = f2bf(acc[n][3]);
            *(ushort4*)(h2 + ((size_t)(c >> 3) * N_NODES + node) * 32 + (c & 7) * 4) = o;
        }
        ps[n] = acc[n][0] * av.x + acc[n][1] * av.y + acc[n][2] * av.z + acc[n][3] * av.w;
        pd[n] = acc[n][0] * dv.x + acc[n][1] * dv.y + acc[n][2] * dv.z + acc[n][3] * dv.w;
    }
    #pragma unroll
    for (int mask = 1; mask <= 2; mask <<= 1) {
        #pragma unroll
        for (int n = 0; n < 4; n++) {
            ps[n] += __shfl_xor(ps[n], mask, 64);
            pd[n] += __shfl_xor(pd[n], mask, 64);
        }
    }
    if ((c & 3) == 0) {
        int hh = c >> 2;
        #pragma unroll
        for (int n = 0; n < 4; n++) {
            int node = node0 + g * 4 + n;
            if (node < N_NODES) {
                as[(size_t)hh * N_NODES + node] = ps[n];
                ad[(size_t)hh * N_NODES + node] = pd[n];
            }
        }
    }
}

// ================================================================ layer-1 gather: 4 head-passes, L2-resident slices,
// wave = 1 node; lane = e(2)|d(4); lanes 0-7 compute the 8 batch weights (1 exp instr / 8 edges), shfl-broadcast
__global__ __launch_bounds__(256) void k_gather1(const int* __restrict__ esrc,
                                                 const int* __restrict__ rowptr,
                                                 const unsigned int* __restrict__ h1s,  // [4][N][16] dwords
                                                 const float* __restrict__ as,          // [4][N]
                                                 const float* __restrict__ ad,          // [4][N]
                                                 const float* __restrict__ b1,
                                                 unsigned int* __restrict__ out1) {     // [N][64] dwords
    int t = threadIdx.x;
    int blk = blockIdx.x;
    int pass = blk / PB;                  // pass-major: 3.2 MB slice stays L2-resident
    int bi = blk - pass * PB;
    int lane = t & 63;
    int e = lane >> 4, d = lane & 15;
    int j = lane & 7;
    int node = bi * 4 + (t >> 6);
    int beg = rowptr[node], end = rowptr[node + 1];
    const unsigned int* tab = h1s + (size_t)pass * N_NODES * 16;
    const float* asp = as + (size_t)pass * N_NODES;
    float adn = ad[(size_t)pass * N_NODES + node];
    float ax = 0.f, ay = 0.f, sw = 0.f;
    for (int k = beg; k < end; k += 8) {
        int sm = esrc[k + j];                       // pad makes this safe unguarded
        float wm = edge_w(asp[sm], adn);
        if (k + j >= end) wm = 0.f;                 // tail masking at source lane
        int sa = __shfl(sm, e, 64);
        int sb = __shfl(sm, 4 + e, 64);
        unsigned int ua = tab[(size_t)sa * 16 + d];
        unsigned int ub = tab[(size_t)sb * 16 + d];
        float wa = __shfl(wm, e, 64);
        float wb = __shfl(wm, 4 + e, 64);
        ax += bf_lo(ua) * wa + bf_lo(ub) * wb;
        ay += bf_hi(ua) * wa + bf_hi(ub) * wb;
        sw += wa + wb;
    }
    // reduce across the 4 edge-slot groups (lane bits 4,5)
    ax += __shfl_xor(ax, 16, 64); ax += __shfl_xor(ax, 32, 64);
    ay += __shfl_xor(ay, 16, 64); ay += __shfl_xor(ay, 32, 64);
    sw += __shfl_xor(sw, 16, 64); sw += __shfl_xor(sw, 32, 64);
    float rs = 1.0f / (sw + 1e-16f);
    float2 bv = *(const float2*)(b1 + pass * 32 + 2 * d);
    float vx = ax * rs + bv.x;
    float vy = ay * rs + bv.y;
    vx = (vx > 0.f) ? vx : (__expf(vx) - 1.0f);   // ELU
    vy = (vy > 0.f) ? vy : (__expf(vy) - 1.0f);
    if (e == 0)
        out1[(size_t)node * 64 + pass * 16 + d] = ((unsigned int)f2bf(vy) << 16) | (unsigned int)f2bf(vx);
}

// ================================================================ layer-2 gather: 2 head-pair passes -> per-pass partials
// lanes 0-15 compute the 8 edges x 2 heads weights, shfl-broadcast
__global__ __launch_bounds__(256) void k_gather2(const int* __restrict__ esrc,
                                                 const int* __restrict__ rowptr,
                                                 const unsigned int* __restrict__ h2s,  // [2][N][16] dwords
                                                 const float* __restrict__ as,          // [4][N]
                                                 const float* __restrict__ ad,          // [4][N]
                                                 float* __restrict__ part) {            // [2][N][16]
    int t = threadIdx.x;
    int blk = blockIdx.x;
    int pass = blk / PB;                  // 0..1
    int bi = blk - pass * PB;
    int lane = t & 63;
    int e = lane >> 4, d = lane & 15;
    int j = lane & 7;
    int hh = (lane >> 3) & 1;             // computing lane's head within pair
    int hd = d >> 3;                      // accumulating lane's head within pair
    int node = bi * 4 + (t >> 6);
    int beg = rowptr[node], end = rowptr[node + 1];
    const unsigned int* tab = h2s + (size_t)pass * N_NODES * 16;
    const float* asp = as + (size_t)(2 * pass + hh) * N_NODES;
    float adn = ad[(size_t)(2 * pass + hh) * N_NODES + node];
    float ax = 0.f, ay = 0.f, sw = 0.f;
    for (int k = beg; k < end; k += 8) {
        int sm = esrc[k + j];
        float wm = edge_w(asp[sm], adn);            // lanes 0-15: 8 edges x 2 heads
        if (k + j >= end) wm = 0.f;
        int sa = __shfl(sm, e, 64);
        int sb = __shfl(sm, 4 + e, 64);
        unsigned int ua = tab[(size_t)sa * 16 + d];
        unsigned int ub = tab[(size_t)sb * 16 + d];
        float wa = __shfl(wm, hd * 8 + e, 64);
        float wb = __shfl(wm, hd * 8 + 4 + e, 64);
        ax += bf_lo(ua) * wa + bf_lo(ub) * wb;
        ay += bf_hi(ua) * wa + bf_hi(ub) * wb;
        sw += wa + wb;
    }
    ax += __shfl_xor(ax, 16, 64); ax += __shfl_xor(ax, 32, 64);
    ay += __shfl_xor(ay, 16, 64); ay += __shfl_xor(ay, 32, 64);
    sw += __shfl_xor(sw, 16, 64); sw += __shfl_xor(sw, 32, 64);
    float rs = 1.0f / (sw + 1e-16f);
    float vx = ax * rs, vy = ay * rs;
    // sum the pass's two heads: lanes d and d^8 hold same classes
    vx += __shfl_xor(vx, 8, 64);
    vy += __shfl_xor(vy, 8, 64);
    if (e == 0 && d < 8)
        *(float2*)(part + ((size_t)pass * N_NODES + node) * 16 + 2 * d) = make_float2(vx, vy);
}

// ================================================================ final: head-mean + b2 + log_softmax
__global__ __launch_bounds__(256) void k_out(const float* __restrict__ part,  // [2][N][16]
                                             const float* __restrict__ b2,
                                             float* __restrict__ out) {
    int t = threadIdx.x;
    int node = blockIdx.x * 16 + (t >> 4);
    int c = t & 15;
    float v = (part[(size_t)node * 16 + c] + part[((size_t)N_NODES + node) * 16 + c]) * 0.25f + b2[c];
    float m = v;
    #pragma unroll
    for (int mask = 1; mask < 16; mask <<= 1) m = fmaxf(m, __shfl_xor(m, mask, 64));
    float ex = __expf(v - m);
    float se = ex;
    #pragma unroll
    for (int mask = 1; mask < 16; mask <<= 1) se += __shfl_xor(se, mask, 64);
    out[(size_t)node * 16 + c] = (v - m) - __logf(se);
}

// ================================================================ host
extern "C" void kernel_launch(void* const* d_in, const int* in_sizes, int n_in,
                              void* d_out, int out_size, void* d_ws, size_t ws_size,
                              hipStream_t stream) {
    const float* x      = (const float*)d_in[0];
    const int*   ei     = (const int*)d_in[1];
    const float* Wemb   = (const float*)d_in[2];
    const float* bemb   = (const float*)d_in[3];
    const float* W1     = (const float*)d_in[4];
    const float* a_src1 = (const float*)d_in[5];
    const float* a_dst1 = (const float*)d_in[6];
    const float* b1     = (const float*)d_in[7];
    const float* W2     = (const float*)d_in[8];
    const float* a_src2 = (const float*)d_in[9];
    const float* a_dst2 = (const float*)d_in[10];
    const float* b2     = (const float*)d_in[11];
    float* out = (float*)d_out;

    char* ws = (char*)d_ws;
    size_t off = 0;
    auto alloc = [&](size_t bytes) { char* p = ws + off; off += (bytes + 255) & ~size_t(255); return p; };
    unsigned short* h1b   = (unsigned short*)alloc((size_t)N_NODES * 128 * 2);  // [4][N][32]; h2s+part overlay after gather1
    unsigned int*   out1b = (unsigned int*)alloc((size_t)N_NODES * 64 * 4);     // [N][64] bf16x2
    float*        h0    = (float*)alloc((size_t)N_NODES * HID * 4);
    int*          esrc  = (int*)alloc((size_t)N_EDGES * 4 + 64);
    unsigned int* pairs = (unsigned int*)alloc((size_t)NBKT * CAP * 4);
    float* as     = (float*)alloc((size_t)N_NODES * 4 * 4);   // [4][N]
    float* ad     = (float*)alloc((size_t)N_NODES * 4 * 4);   // [4][N]
    int*   rowptr = (int*)alloc((size_t)(N_NODES + 1) * 4);
    int*   gcnt   = (int*)alloc((size_t)NBKT * 4);
    unsigned short* h2b  = h1b;                                        // [2][N][32], first 6.4 MB of h1b
    float*          part = (float*)(h1b + (size_t)N_NODES * 64);       // [2][N][16] fp32, second 6.4 MB

    hipMemsetAsync(gcnt, 0, (size_t)NBKT * 4, stream);
    k_F1<<<NB64 + NBKT, 256, 0, stream>>>(x, Wemb, bemb, h0, ei, gcnt, pairs, esrc);
    k_F2<<<NB64 + NBKT, 256, 0, stream>>>(h0, W1, a_src1, a_dst1, h1b, as, ad,
                                          pairs, gcnt, rowptr, esrc);
    k_gather1<<<4 * PB, 256, 0, stream>>>(esrc, rowptr, (const unsigned int*)h1b, as, ad, b1, out1b);
    k_h2f<<<NB64, 256, 0, stream>>>(out1b, W2, a_src2, a_dst2, h2b, as, ad);
    k_gather2<<<2 * PB, 256, 0, stream>>>(esrc, rowptr, (const unsigned int*)h2b, as, ad, part);
    k_out<<<N_NODES / 16, 256, 0, stream>>>(part, b2, out);
}

// Round 10
// 225.023 us; speedup vs baseline: 1.2497x; 1.2497x over previous
//
#include <hip/hip_runtime.h>

#define N_NODES 50000
#define N_EDGES 800000
#define F_IN    128
#define HID     32
#define HEADS   4
#define OUT_C   16

#define NBKT 196      // buckets = dst>>8 ; 196*256 = 50176 >= N_NODES
#define CAP  5120     // per-bucket capacity; mean 4082
#define EPB  4096     // edges per bucketA block; 196 blocks cover 802816
#define NB64 782      // ceil(N_NODES/64)

// bf16 helpers (RNE)
__device__ __forceinline__ unsigned short f2bf(float f) {
    unsigned int u = __float_as_uint(f);
    u += 0x7FFFu + ((u >> 16) & 1u);
    return (unsigned short)(u >> 16);
}
__device__ __forceinline__ float bf_lo(unsigned int u) { return __uint_as_float(u << 16); }
__device__ __forceinline__ float bf_hi(unsigned int u) { return __uint_as_float(u & 0xFFFF0000u); }
__device__ __forceinline__ float bf2f(unsigned short s) {
    return __uint_as_float(((unsigned int)s) << 16);
}

__device__ __forceinline__ float edge_w(float asv, float adv) {
    float v = asv + adv;
    v = (v > 0.f) ? v : 0.2f * v;        // leaky_relu(0.2)
    return __expf(v);                    // softmax shift-invariant; logits O(1)
}

// ================================================================ F1 = k_emb (h0 = x@Wemb+bemb) ∪ bucketA
__global__ __launch_bounds__(256) void k_F1(const float* __restrict__ x,
                                            const float* __restrict__ Wemb,
                                            const float* __restrict__ bemb,
                                            float* __restrict__ h0,
                                            const int* __restrict__ ei,
                                            int* __restrict__ gcnt,
                                            unsigned int* __restrict__ pairs,
                                            int* __restrict__ esrc) {
    __shared__ float xs[64][132];
    __shared__ float Wl[F_IN][HID];
    __shared__ float bl[HID];
    __shared__ int hist[NBKT];
    __shared__ int base[NBKT];
    int t = threadIdx.x;
    if (blockIdx.x < NB64) {
        int node0 = blockIdx.x * 64;
        if (t < HID) bl[t] = bemb[t];
        #pragma unroll
        for (int it = 0; it < 4; it++) {
            int idx = it * 256 + t;
            *(float4*)((float*)Wl + idx * 4) = *(const float4*)(Wemb + idx * 4);
        }
        #pragma unroll
        for (int it = 0; it < 8; it++) {
            int idx = it * 256 + t;
            int row = idx >> 5, c4 = idx & 31;
            float4 v = make_float4(0.f, 0.f, 0.f, 0.f);
            if (node0 + row < N_NODES) v = *(const float4*)(x + (size_t)(node0 + row) * F_IN + c4 * 4);
            *(float4*)&xs[row][c4 * 4] = v;
        }
        __syncthreads();
        int c = t & 7, g = t >> 3;
        float acc[2][4] = {};
        for (int k = 0; k < F_IN; k++) {
            float4 w4 = *(const float4*)&Wl[k][c * 4];
            #pragma unroll
            for (int n = 0; n < 2; n++) {
                float xv = xs[g * 2 + n][k];
                acc[n][0] += xv * w4.x; acc[n][1] += xv * w4.y;
                acc[n][2] += xv * w4.z; acc[n][3] += xv * w4.w;
            }
        }
        #pragma unroll
        for (int n = 0; n < 2; n++) {
            int node = node0 + g * 2 + n;
            if (node < N_NODES) {
                float4 o = make_float4(acc[n][0] + bl[c * 4], acc[n][1] + bl[c * 4 + 1],
                                       acc[n][2] + bl[c * 4 + 2], acc[n][3] + bl[c * 4 + 3]);
                *(float4*)(h0 + (size_t)node * HID + c * 4) = o;
            }
        }
    } else {
        if (blockIdx.x == NB64 && t < 32) esrc[N_EDGES + t] = 0;   // pad: gathers drop tail clamps
        int e0 = (blockIdx.x - NB64) * EPB;
        for (int i = t; i < NBKT; i += 256) hist[i] = 0;
        __syncthreads();
        unsigned int p[16];
        int bb[16];
        #pragma unroll
        for (int i = 0; i < 16; i++) {
            int e = e0 + i * 256 + t;
            bb[i] = -1;
            if (e < N_EDGES) {
                int s = ei[e], d = ei[N_EDGES + e];
                p[i] = ((unsigned int)s << 8) | (unsigned int)(d & 255);
                bb[i] = d >> 8;
                atomicAdd(&hist[bb[i]], 1);
            }
        }
        __syncthreads();
        for (int i = t; i < NBKT; i += 256) {
            int c = hist[i];
            base[i] = i * CAP + (c ? atomicAdd(&gcnt[i], c) : 0);
            hist[i] = 0;
        }
        __syncthreads();
        #pragma unroll
        for (int i = 0; i < 16; i++) {
            if (bb[i] >= 0) {
                int off = atomicAdd(&hist[bb[i]], 1);
                pairs[base[bb[i]] + off] = p[i];
            }
        }
    }
}

// ================================================================ F2 = h1f (h1=h0@W1, bf16 + alpha dots) ∪ bucketB
__global__ __launch_bounds__(256) void k_F2(const float* __restrict__ h0,
                                            const float* __restrict__ W1,
                                            const float* __restrict__ a_src,
                                            const float* __restrict__ a_dst,
                                            unsigned short* __restrict__ h1,   // [N][128] bf16
                                            float* __restrict__ as, float* __restrict__ ad,  // [N][4]
                                            const unsigned int* __restrict__ pairs,
                                            const int* __restrict__ gcnt,
                                            int* __restrict__ rowptr,
                                            int* __restrict__ esrc) {
    __shared__ float xs[64][36];
    __shared__ float Wl[HID][128];
    __shared__ int cnt[256];
    __shared__ int cur[256];
    __shared__ int wsum[4];
    int t = threadIdx.x;
    if (blockIdx.x < NB64) {
        int node0 = blockIdx.x * 64;
        #pragma unroll
        for (int it = 0; it < 4; it++) {
            int idx = it * 256 + t;
            *(float4*)((float*)Wl + idx * 4) = *(const float4*)(W1 + idx * 4);
        }
        #pragma unroll
        for (int it = 0; it < 2; it++) {
            int idx = it * 256 + t;
            int row = idx >> 3, c4 = idx & 7;
            float4 v = make_float4(0.f, 0.f, 0.f, 0.f);
            if (node0 + row < N_NODES) v = *(const float4*)(h0 + (size_t)(node0 + row) * HID + c4 * 4);
            *(float4*)&xs[row][c4 * 4] = v;
        }
        __syncthreads();
        int c = t & 31, g = t >> 5;
        float acc[8][4] = {};
        for (int k = 0; k < HID; k++) {
            float4 w4 = *(const float4*)&Wl[k][c * 4];
            #pragma unroll
            for (int n = 0; n < 8; n++) {
                float xv = xs[g * 8 + n][k];
                acc[n][0] += xv * w4.x; acc[n][1] += xv * w4.y;
                acc[n][2] += xv * w4.z; acc[n][3] += xv * w4.w;
            }
        }
        float4 av = *(const float4*)(a_src + c * 4);
        float4 dv = *(const float4*)(a_dst + c * 4);
        float ps[8], pd[8];
        #pragma unroll
        for (int n = 0; n < 8; n++) {
            int node = node0 + g * 8 + n;
            if (node < N_NODES) {
                ushort4 o;
                o.x = f2bf(acc[n][0]); o.y = f2bf(acc[n][1]);
                o.z = f2bf(acc[n][2]); o.w = f2bf(acc[n][3]);
                *(ushort4*)(h1 + (size_t)node * 128 + c * 4) = o;
            }
            ps[n] = acc[n][0] * av.x + acc[n][1] * av.y + acc[n][2] * av.z + acc[n][3] * av.w;
            pd[n] = acc[n][0] * dv.x + acc[n][1] * dv.y + acc[n][2] * dv.z + acc[n][3] * dv.w;
        }
        #pragma unroll
        for (int mask = 1; mask <= 4; mask <<= 1) {
            #pragma unroll
            for (int n = 0; n < 8; n++) {
                ps[n] += __shfl_xor(ps[n], mask, 64);
                pd[n] += __shfl_xor(pd[n], mask, 64);
            }
        }
        if ((c & 7) == 0) {
            int hh = c >> 3;
            #pragma unroll
            for (int n = 0; n < 8; n++) {
                int node = node0 + g * 8 + n;
                if (node < N_NODES) { as[node * 4 + hh] = ps[n]; ad[node * 4 + hh] = pd[n]; }
            }
        }
    } else {
        int b = blockIdx.x - NB64;
        int lane = t & 63, wv = t >> 6;
        int v0 = (t < NBKT && t < b) ? gcnt[t] : 0;
        #pragma unroll
        for (int mask = 1; mask < 64; mask <<= 1) v0 += __shfl_xor(v0, mask, 64);
        if (lane == 0) wsum[wv] = v0;
        __syncthreads();
        int base = wsum[0] + wsum[1] + wsum[2] + wsum[3];
        int n0 = b << 8;
        int cntb = gcnt[b];
        int s0 = b * CAP;
        cnt[t] = 0;
        __syncthreads();
        for (int i = t; i < cntb; i += 256) atomicAdd(&cnt[pairs[s0 + i] & 255], 1);
        __syncthreads();
        int v = cnt[t], x = v;
        #pragma unroll
        for (int off = 1; off < 64; off <<= 1) { int y = __shfl_up(x, off, 64); if (lane >= off) x += y; }
        __syncthreads();
        if (lane == 63) wsum[wv] = x;
        __syncthreads();
        int add = 0;
        for (int j = 0; j < wv; j++) add += wsum[j];
        int excl = base + (x - v) + add;
        cur[t] = excl;
        if (n0 + t < N_NODES) rowptr[n0 + t] = excl;
        if (b == 0 && t == 0) rowptr[N_NODES] = N_EDGES;
        __syncthreads();
        for (int i = t; i < cntb; i += 256) {
            unsigned int p = pairs[s0 + i];
            int pos = atomicAdd(&cur[p & 255], 1);
            esrc[pos] = (int)(p >> 8);
        }
    }
}

// ================================================================ h2 = out1(bf16) @ W2 (bf16 out) + fused alpha2
__global__ __launch_bounds__(256) void k_h2f(const unsigned int* __restrict__ hin,  // [N][64] bf16x2
                                             const float* __restrict__ W2,
                                             const float* __restrict__ a_src,
                                             const float* __restrict__ a_dst,
                                             unsigned short* __restrict__ h2,       // [N][64] bf16
                                             float* __restrict__ as, float* __restrict__ ad) {
    __shared__ float xs[64][132];
    __shared__ float Wl[128][64];
    int t = threadIdx.x;
    int node0 = blockIdx.x * 64;
    #pragma unroll
    for (int it = 0; it < 8; it++) {
        int idx = it * 256 + t;
        *(float4*)((float*)Wl + idx * 4) = *(const float4*)(W2 + idx * 4);
    }
    #pragma unroll
    for (int it = 0; it < 8; it++) {
        int idx = it * 256 + t;
        int row = idx >> 5, c4 = idx & 31;
        float4 v = make_float4(0.f, 0.f, 0.f, 0.f);
        if (node0 + row < N_NODES) {
            uint2 u = *(const uint2*)(hin + (size_t)(node0 + row) * 64 + c4 * 2);
            v = make_float4(bf_lo(u.x), bf_hi(u.x), bf_lo(u.y), bf_hi(u.y));
        }
        *(float4*)&xs[row][c4 * 4] = v;
    }
    __syncthreads();
    int c = t & 15, g = t >> 4;
    float acc[4][4] = {};
    for (int k = 0; k < 128; k++) {
        float4 w4 = *(const float4*)&Wl[k][c * 4];
        #pragma unroll
        for (int n = 0; n < 4; n++) {
            float xv = xs[g * 4 + n][k];
            acc[n][0] += xv * w4.x; acc[n][1] += xv * w4.y;
            acc[n][2] += xv * w4.z; acc[n][3] += xv * w4.w;
        }
    }
    float4 av = *(const float4*)(a_src + c * 4);
    float4 dv = *(const float4*)(a_dst + c * 4);
    float ps[4], pd[4];
    #pragma unroll
    for (int n = 0; n < 4; n++) {
        int node = node0 + g * 4 + n;
        if (node < N_NODES) {
            ushort4 o;
            o.x = f2bf(acc[n][0]); o.y = f2bf(acc[n][1]);
            o.z = f2bf(acc[n][2]); o.w = f2bf(acc[n][3]);
            *(ushort4*)(h2 + (size_t)node * 64 + c * 4) = o;
        }
        ps[n] = acc[n][0] * av.x + acc[n][1] * av.y + acc[n][2] * av.z + acc[n][3] * av.w;
        pd[n] = acc[n][0] * dv.x + acc[n][1] * dv.y + acc[n][2] * dv.z + acc[n][3] * dv.w;
    }
    #pragma unroll
    for (int mask = 1; mask <= 2; mask <<= 1) {
        #pragma unroll
        for (int n = 0; n < 4; n++) {
            ps[n] += __shfl_xor(ps[n], mask, 64);
            pd[n] += __shfl_xor(pd[n], mask, 64);
        }
    }
    if ((c & 3) == 0) {
        int hh = c >> 2;
        #pragma unroll
        for (int n = 0; n < 4; n++) {
            int node = node0 + g * 4 + n;
            if (node < N_NODES) { as[node * 4 + hh] = ps[n]; ad[node * 4 + hh] = pd[n]; }
        }
    }
}

// ================================================================ layer-1 gather: 16-edge batches, one chain per mean-degree node
// w-lanes: lane = edge(lane>>2) x head(lane&3); channel lanes: dword `lane`, head = lane>>4
__global__ __launch_bounds__(256) void k_gather1(const int* __restrict__ esrc,
                                                 const int* __restrict__ rowptr,
                                                 const unsigned int* __restrict__ h1,   // [N][64] bf16x2
                                                 const float* __restrict__ as,          // [N][4]
                                                 const float* __restrict__ ad,          // [N][4]
                                                 const float* __restrict__ b1,
                                                 unsigned int* __restrict__ out1) {     // [N][64] bf16x2
    int t = threadIdx.x;
    int node = blockIdx.x * 4 + (t >> 6);
    int lane = t & 63;
    int head = lane >> 4;
    int j = lane >> 2;                   // edge slot 0..15 (for w computation)
    int h4 = lane & 3;                   // head for w computation
    int beg = rowptr[node], end = rowptr[node + 1];
    float ad_w = ad[node * 4 + h4];
    float ax = 0.f, ay = 0.f, sw = 0.f;
    int ids = esrc[beg + j];             // esrc padded: safe unguarded
    for (int k = beg; k < end; k += 16) {
        float asv = as[ids * 4 + h4];    // issue first: overlaps row loads
        unsigned u[16];
        #pragma unroll
        for (int i = 0; i < 16; i++)     // 16 rows in flight together
            u[i] = h1[(size_t)__shfl(ids, 4 * i, 64) * 64 + lane];
        int ids_n = esrc[k + 16 + j];    // prefetch next batch ids
        float wm = edge_w(asv, ad_w);
        if (k + j >= end) wm = 0.f;      // tail masking at source lane
        #pragma unroll
        for (int i = 0; i < 16; i++) {
            float wi = __shfl(wm, 4 * i + head, 64);
            ax += bf_lo(u[i]) * wi;
            ay += bf_hi(u[i]) * wi;
            sw += wi;
        }
        ids = ids_n;
    }
    float rs = 1.0f / (sw + 1e-16f);
    float2 bv = *(const float2*)(b1 + 2 * lane);
    float vx = ax * rs + bv.x;
    float vy = ay * rs + bv.y;
    vx = (vx > 0.f) ? vx : (__expf(vx) - 1.0f);   // ELU
    vy = (vy > 0.f) ? vy : (__expf(vy) - 1.0f);
    out1[(size_t)node * 64 + lane] = ((unsigned int)f2bf(vy) << 16) | (unsigned int)f2bf(vx);
}

// ================================================================ layer-2 gather + head-mean + b2 + log_softmax
__global__ __launch_bounds__(256) void k_gather2(const int* __restrict__ esrc,
                                                 const int* __restrict__ rowptr,
                                                 const unsigned short* __restrict__ h2,  // [N][64] bf16
                                                 const float* __restrict__ as,           // [N][4]
                                                 const float* __restrict__ ad,           // [N][4]
                                                 const float* __restrict__ b2,
                                                 float* __restrict__ out) {
    int t = threadIdx.x;
    int node = blockIdx.x * 4 + (t >> 6);
    int lane = t & 63;
    int head = lane >> 4, c = lane & 15;
    int j = lane >> 2;
    int h4 = lane & 3;
    int beg = rowptr[node], end = rowptr[node + 1];
    float ad_w = ad[node * 4 + h4];
    float acc = 0.f, sw = 0.f;
    int ids = esrc[beg + j];
    for (int k = beg; k < end; k += 16) {
        float asv = as[ids * 4 + h4];
        float r[16];
        #pragma unroll
        for (int i = 0; i < 16; i++)
            r[i] = bf2f(h2[(size_t)__shfl(ids, 4 * i, 64) * 64 + lane]);
        int ids_n = esrc[k + 16 + j];
        float wm = edge_w(asv, ad_w);
        if (k + j >= end) wm = 0.f;
        #pragma unroll
        for (int i = 0; i < 16; i++) {
            float wi = __shfl(wm, 4 * i + head, 64);
            acc += r[i] * wi;
            sw += wi;
        }
        ids = ids_n;
    }
    float v = acc * (1.0f / (sw + 1e-16f));
    v += __shfl_xor(v, 16, 64);          // mean over 4 heads
    v += __shfl_xor(v, 32, 64);
    v = v * 0.25f + b2[c];
    float m = v;                         // log_softmax over 16 classes
    #pragma unroll
    for (int mask = 1; mask < 16; mask <<= 1) m = fmaxf(m, __shfl_xor(m, mask, 64));
    float ex = __expf(v - m);
    float se = ex;
    #pragma unroll
    for (int mask = 1; mask < 16; mask <<= 1) se += __shfl_xor(se, mask, 64);
    float res = (v - m) - __logf(se);
    if (lane < 16) out[(size_t)node * 16 + lane] = res;
}

// ================================================================ host
extern "C" void kernel_launch(void* const* d_in, const int* in_sizes, int n_in,
                              void* d_out, int out_size, void* d_ws, size_t ws_size,
                              hipStream_t stream) {
    const float* x      = (const float*)d_in[0];
    const int*   ei     = (const int*)d_in[1];
    const float* Wemb   = (const float*)d_in[2];
    const float* bemb   = (const float*)d_in[3];
    const float* W1     = (const float*)d_in[4];
    const float* a_src1 = (const float*)d_in[5];
    const float* a_dst1 = (const float*)d_in[6];
    const float* b1     = (const float*)d_in[7];
    const float* W2     = (const float*)d_in[8];
    const float* a_src2 = (const float*)d_in[9];
    const float* a_dst2 = (const float*)d_in[10];
    const float* b2     = (const float*)d_in[11];
    float* out = (float*)d_out;

    char* ws = (char*)d_ws;
    size_t off = 0;
    auto alloc = [&](size_t bytes) { char* p = ws + off; off += (bytes + 255) & ~size_t(255); return p; };
    unsigned short* h1b   = (unsigned short*)alloc((size_t)N_NODES * 128 * 2);  // h2b [N][64] overlays front
    unsigned int*   out1b = (unsigned int*)alloc((size_t)N_NODES * 64 * 4);     // [N][64] bf16x2
    float*        h0    = (float*)alloc((size_t)N_NODES * HID * 4);
    int*          esrc  = (int*)alloc((size_t)N_EDGES * 4 + 256);               // +32 pad ints
    unsigned int* pairs = (unsigned int*)alloc((size_t)NBKT * CAP * 4);
    float* as     = (float*)alloc((size_t)N_NODES * 4 * 4);   // [N][4]
    float* ad     = (float*)alloc((size_t)N_NODES * 4 * 4);   // [N][4]
    int*   rowptr = (int*)alloc((size_t)(N_NODES + 1) * 4);
    int*   gcnt   = (int*)alloc((size_t)NBKT * 4);
    unsigned short* h2b = h1b;     // h1b dead after gather1

    const int GB = N_NODES / 4;    // 12500

    hipMemsetAsync(gcnt, 0, (size_t)NBKT * 4, stream);
    k_F1<<<NB64 + NBKT, 256, 0, stream>>>(x, Wemb, bemb, h0, ei, gcnt, pairs, esrc);
    k_F2<<<NB64 + NBKT, 256, 0, stream>>>(h0, W1, a_src1, a_dst1, h1b, as, ad,
                                          pairs, gcnt, rowptr, esrc);
    k_gather1<<<GB, 256, 0, stream>>>(esrc, rowptr, (const unsigned int*)h1b, as, ad, b1, out1b);
    k_h2f<<<NB64, 256, 0, stream>>>(out1b, W2, a_src2, a_dst2, h2b, as, ad);
    k_gather2<<<GB, 256, 0, stream>>>(esrc, rowptr, h2b, as, ad, b2, out);
}

// Round 11
// 215.423 us; speedup vs baseline: 1.3054x; 1.0446x over previous
//
#include <hip/hip_runtime.h>

#define N_NODES 50000
#define N_EDGES 800000
#define F_IN    128
#define HID     32
#define HEADS   4
#define OUT_C   16

#define NBKT 196      // buckets = dst>>8 ; 196*256 = 50176 >= N_NODES
#define CAP  5120     // per-bucket capacity; mean 4082
#define EPB  4096     // edges per bucketA block; 196 blocks cover 802816
#define NB64 782      // ceil(N_NODES/64)

// bf16 helpers (RNE)
__device__ __forceinline__ unsigned short f2bf(float f) {
    unsigned int u = __float_as_uint(f);
    u += 0x7FFFu + ((u >> 16) & 1u);
    return (unsigned short)(u >> 16);
}
__device__ __forceinline__ float bf_lo(unsigned int u) { return __uint_as_float(u << 16); }
__device__ __forceinline__ float bf_hi(unsigned int u) { return __uint_as_float(u & 0xFFFF0000u); }

__device__ __forceinline__ float edge_w(float asv, float adv) {
    float v = asv + adv;
    v = (v > 0.f) ? v : 0.2f * v;        // leaky_relu(0.2)
    return __expf(v);                    // softmax shift-invariant; logits O(1)
}

// ================================================================ F1 = k_emb (h0 = x@Wemb+bemb) ∪ bucketA
__global__ __launch_bounds__(256) void k_F1(const float* __restrict__ x,
                                            const float* __restrict__ Wemb,
                                            const float* __restrict__ bemb,
                                            float* __restrict__ h0,
                                            const int* __restrict__ ei,
                                            int* __restrict__ gcnt,
                                            unsigned int* __restrict__ pairs,
                                            int* __restrict__ esrc) {
    __shared__ float xs[64][132];
    __shared__ float Wl[F_IN][HID];
    __shared__ float bl[HID];
    __shared__ int hist[NBKT];
    __shared__ int base[NBKT];
    int t = threadIdx.x;
    if (blockIdx.x < NB64) {
        int node0 = blockIdx.x * 64;
        if (t < HID) bl[t] = bemb[t];
        #pragma unroll
        for (int it = 0; it < 4; it++) {
            int idx = it * 256 + t;
            *(float4*)((float*)Wl + idx * 4) = *(const float4*)(Wemb + idx * 4);
        }
        #pragma unroll
        for (int it = 0; it < 8; it++) {
            int idx = it * 256 + t;
            int row = idx >> 5, c4 = idx & 31;
            float4 v = make_float4(0.f, 0.f, 0.f, 0.f);
            if (node0 + row < N_NODES) v = *(const float4*)(x + (size_t)(node0 + row) * F_IN + c4 * 4);
            *(float4*)&xs[row][c4 * 4] = v;
        }
        __syncthreads();
        int c = t & 7, g = t >> 3;
        float acc[2][4] = {};
        for (int k = 0; k < F_IN; k++) {
            float4 w4 = *(const float4*)&Wl[k][c * 4];
            #pragma unroll
            for (int n = 0; n < 2; n++) {
                float xv = xs[g * 2 + n][k];
                acc[n][0] += xv * w4.x; acc[n][1] += xv * w4.y;
                acc[n][2] += xv * w4.z; acc[n][3] += xv * w4.w;
            }
        }
        #pragma unroll
        for (int n = 0; n < 2; n++) {
            int node = node0 + g * 2 + n;
            if (node < N_NODES) {
                float4 o = make_float4(acc[n][0] + bl[c * 4], acc[n][1] + bl[c * 4 + 1],
                                       acc[n][2] + bl[c * 4 + 2], acc[n][3] + bl[c * 4 + 3]);
                *(float4*)(h0 + (size_t)node * HID + c * 4) = o;
            }
        }
    } else {
        if (blockIdx.x == NB64 && t < 32) esrc[N_EDGES + t] = 0;   // pad: gathers drop tail clamps
        int e0 = (blockIdx.x - NB64) * EPB;
        for (int i = t; i < NBKT; i += 256) hist[i] = 0;
        __syncthreads();
        unsigned int p[16];
        int bb[16];
        #pragma unroll
        for (int i = 0; i < 16; i++) {
            int e = e0 + i * 256 + t;
            bb[i] = -1;
            if (e < N_EDGES) {
                int s = ei[e], d = ei[N_EDGES + e];
                p[i] = ((unsigned int)s << 8) | (unsigned int)(d & 255);
                bb[i] = d >> 8;
                atomicAdd(&hist[bb[i]], 1);
            }
        }
        __syncthreads();
        for (int i = t; i < NBKT; i += 256) {
            int c = hist[i];
            base[i] = i * CAP + (c ? atomicAdd(&gcnt[i], c) : 0);
            hist[i] = 0;
        }
        __syncthreads();
        #pragma unroll
        for (int i = 0; i < 16; i++) {
            if (bb[i] >= 0) {
                int off = atomicAdd(&hist[bb[i]], 1);
                pairs[base[bb[i]] + off] = p[i];
            }
        }
    }
}

// ================================================================ F2 = h1f (h1=h0@W1, bf16 + alpha dots) ∪ bucketB
__global__ __launch_bounds__(256) void k_F2(const float* __restrict__ h0,
                                            const float* __restrict__ W1,
                                            const float* __restrict__ a_src,
                                            const float* __restrict__ a_dst,
                                            unsigned short* __restrict__ h1,   // [N][128] bf16
                                            float* __restrict__ as, float* __restrict__ ad,  // [N][4]
                                            const unsigned int* __restrict__ pairs,
                                            const int* __restrict__ gcnt,
                                            int* __restrict__ rowptr,
                                            int* __restrict__ esrc) {
    __shared__ float xs[64][36];
    __shared__ float Wl[HID][128];
    __shared__ int cnt[256];
    __shared__ int cur[256];
    __shared__ int wsum[4];
    int t = threadIdx.x;
    if (blockIdx.x < NB64) {
        int node0 = blockIdx.x * 64;
        #pragma unroll
        for (int it = 0; it < 4; it++) {
            int idx = it * 256 + t;
            *(float4*)((float*)Wl + idx * 4) = *(const float4*)(W1 + idx * 4);
        }
        #pragma unroll
        for (int it = 0; it < 2; it++) {
            int idx = it * 256 + t;
            int row = idx >> 3, c4 = idx & 7;
            float4 v = make_float4(0.f, 0.f, 0.f, 0.f);
            if (node0 + row < N_NODES) v = *(const float4*)(h0 + (size_t)(node0 + row) * HID + c4 * 4);
            *(float4*)&xs[row][c4 * 4] = v;
        }
        __syncthreads();
        int c = t & 31, g = t >> 5;
        float acc[8][4] = {};
        for (int k = 0; k < HID; k++) {
            float4 w4 = *(const float4*)&Wl[k][c * 4];
            #pragma unroll
            for (int n = 0; n < 8; n++) {
                float xv = xs[g * 8 + n][k];
                acc[n][0] += xv * w4.x; acc[n][1] += xv * w4.y;
                acc[n][2] += xv * w4.z; acc[n][3] += xv * w4.w;
            }
        }
        float4 av = *(const float4*)(a_src + c * 4);
        float4 dv = *(const float4*)(a_dst + c * 4);
        float ps[8], pd[8];
        #pragma unroll
        for (int n = 0; n < 8; n++) {
            int node = node0 + g * 8 + n;
            if (node < N_NODES) {
                ushort4 o;
                o.x = f2bf(acc[n][0]); o.y = f2bf(acc[n][1]);
                o.z = f2bf(acc[n][2]); o.w = f2bf(acc[n][3]);
                *(ushort4*)(h1 + (size_t)node * 128 + c * 4) = o;
            }
            ps[n] = acc[n][0] * av.x + acc[n][1] * av.y + acc[n][2] * av.z + acc[n][3] * av.w;
            pd[n] = acc[n][0] * dv.x + acc[n][1] * dv.y + acc[n][2] * dv.z + acc[n][3] * dv.w;
        }
        #pragma unroll
        for (int mask = 1; mask <= 4; mask <<= 1) {
            #pragma unroll
            for (int n = 0; n < 8; n++) {
                ps[n] += __shfl_xor(ps[n], mask, 64);
                pd[n] += __shfl_xor(pd[n], mask, 64);
            }
        }
        if ((c & 7) == 0) {
            int hh = c >> 3;
            #pragma unroll
            for (int n = 0; n < 8; n++) {
                int node = node0 + g * 8 + n;
                if (node < N_NODES) { as[node * 4 + hh] = ps[n]; ad[node * 4 + hh] = pd[n]; }
            }
        }
    } else {
        int b = blockIdx.x - NB64;
        int lane = t & 63, wv = t >> 6;
        int v0 = (t < NBKT && t < b) ? gcnt[t] : 0;
        #pragma unroll
        for (int mask = 1; mask < 64; mask <<= 1) v0 += __shfl_xor(v0, mask, 64);
        if (lane == 0) wsum[wv] = v0;
        __syncthreads();
        int base = wsum[0] + wsum[1] + wsum[2] + wsum[3];
        int n0 = b << 8;
        int cntb = gcnt[b];
        int s0 = b * CAP;
        cnt[t] = 0;
        __syncthreads();
        for (int i = t; i < cntb; i += 256) atomicAdd(&cnt[pairs[s0 + i] & 255], 1);
        __syncthreads();
        int v = cnt[t], x = v;
        #pragma unroll
        for (int off = 1; off < 64; off <<= 1) { int y = __shfl_up(x, off, 64); if (lane >= off) x += y; }
        __syncthreads();
        if (lane == 63) wsum[wv] = x;
        __syncthreads();
        int add = 0;
        for (int j = 0; j < wv; j++) add += wsum[j];
        int excl = base + (x - v) + add;
        cur[t] = excl;
        if (n0 + t < N_NODES) rowptr[n0 + t] = excl;
        if (b == 0 && t == 0) rowptr[N_NODES] = N_EDGES;
        __syncthreads();
        for (int i = t; i < cntb; i += 256) {
            unsigned int p = pairs[s0 + i];
            int pos = atomicAdd(&cur[p & 255], 1);
            esrc[pos] = (int)(p >> 8);
        }
    }
}

// ================================================================ h2 = out1(bf16) @ W2 (bf16 out) + fused alpha2
__global__ __launch_bounds__(256) void k_h2f(const unsigned int* __restrict__ hin,  // [N][64] bf16x2
                                             const float* __restrict__ W2,
                                             const float* __restrict__ a_src,
                                             const float* __restrict__ a_dst,
                                             unsigned short* __restrict__ h2,       // [N][64] bf16
                                             float* __restrict__ as, float* __restrict__ ad) {
    __shared__ float xs[64][132];
    __shared__ float Wl[128][64];
    int t = threadIdx.x;
    int node0 = blockIdx.x * 64;
    #pragma unroll
    for (int it = 0; it < 8; it++) {
        int idx = it * 256 + t;
        *(float4*)((float*)Wl + idx * 4) = *(const float4*)(W2 + idx * 4);
    }
    #pragma unroll
    for (int it = 0; it < 8; it++) {
        int idx = it * 256 + t;
        int row = idx >> 5, c4 = idx & 31;
        float4 v = make_float4(0.f, 0.f, 0.f, 0.f);
        if (node0 + row < N_NODES) {
            uint2 u = *(const uint2*)(hin + (size_t)(node0 + row) * 64 + c4 * 2);
            v = make_float4(bf_lo(u.x), bf_hi(u.x), bf_lo(u.y), bf_hi(u.y));
        }
        *(float4*)&xs[row][c4 * 4] = v;
    }
    __syncthreads();
    int c = t & 15, g = t >> 4;
    float acc[4][4] = {};
    for (int k = 0; k < 128; k++) {
        float4 w4 = *(const float4*)&Wl[k][c * 4];
        #pragma unroll
        for (int n = 0; n < 4; n++) {
            float xv = xs[g * 4 + n][k];
            acc[n][0] += xv * w4.x; acc[n][1] += xv * w4.y;
            acc[n][2] += xv * w4.z; acc[n][3] += xv * w4.w;
        }
    }
    float4 av = *(const float4*)(a_src + c * 4);
    float4 dv = *(const float4*)(a_dst + c * 4);
    float ps[4], pd[4];
    #pragma unroll
    for (int n = 0; n < 4; n++) {
        int node = node0 + g * 4 + n;
        if (node < N_NODES) {
            ushort4 o;
            o.x = f2bf(acc[n][0]); o.y = f2bf(acc[n][1]);
            o.z = f2bf(acc[n][2]); o.w = f2bf(acc[n][3]);
            *(ushort4*)(h2 + (size_t)node * 64 + c * 4) = o;
        }
        ps[n] = acc[n][0] * av.x + acc[n][1] * av.y + acc[n][2] * av.z + acc[n][3] * av.w;
        pd[n] = acc[n][0] * dv.x + acc[n][1] * dv.y + acc[n][2] * dv.z + acc[n][3] * dv.w;
    }
    #pragma unroll
    for (int mask = 1; mask <= 2; mask <<= 1) {
        #pragma unroll
        for (int n = 0; n < 4; n++) {
            ps[n] += __shfl_xor(ps[n], mask, 64);
            pd[n] += __shfl_xor(pd[n], mask, 64);
        }
    }
    if ((c & 3) == 0) {
        int hh = c >> 2;
        #pragma unroll
        for (int n = 0; n < 4; n++) {
            int node = node0 + g * 4 + n;
            if (node < N_NODES) { as[node * 4 + hh] = ps[n]; ad[node * 4 + hh] = pd[n]; }
        }
    }
}

// ================================================================ layer-1 gather: 16-edge batches, uint2 loads (2 rows/instr)
// w-lanes: j=lane>>2 (edge), h4=lane&3 (head). row-lanes: half=lane>>5 (edge parity), d5=lane&31 (uint2 slot), head=d5>>3
__global__ __launch_bounds__(256) void k_gather1(const int* __restrict__ esrc,
                                                 const int* __restrict__ rowptr,
                                                 const unsigned int* __restrict__ h1,   // [N][64] bf16x2
                                                 const float* __restrict__ as,          // [N][4]
                                                 const float* __restrict__ ad,          // [N][4]
                                                 const float* __restrict__ b1,
                                                 unsigned int* __restrict__ out1) {     // [N][64] bf16x2
    int t = threadIdx.x;
    int node = blockIdx.x * 4 + (t >> 6);
    int lane = t & 63;
    int half = lane >> 5, d5 = lane & 31;
    int head = d5 >> 3;
    int j = lane >> 2, h4 = lane & 3;
    int beg = rowptr[node], end = rowptr[node + 1];
    float ad_w = ad[node * 4 + h4];
    float a0 = 0.f, a1 = 0.f, a2 = 0.f, a3 = 0.f, sw = 0.f;
    int ids = esrc[beg + j];             // esrc padded: safe unguarded
    for (int k = beg; k < end; k += 16) {
        float asv = as[ids * 4 + h4];    // issue first: overlaps row loads
        uint2 u[8];
        #pragma unroll
        for (int i = 0; i < 8; i++) {    // pair i = edges (2i, 2i+1); 2 rows per wave-load
            int sa = __shfl(ids, 8 * i, 64);
            int sb = __shfl(ids, 8 * i + 4, 64);
            int row = half ? sb : sa;
            u[i] = *(const uint2*)(h1 + (size_t)row * 64 + 2 * d5);
        }
        int ids_n = esrc[k + 16 + j];    // prefetch next batch ids
        float wm = edge_w(asv, ad_w);
        if (k + j >= end) wm = 0.f;      // tail masking at source lane
        #pragma unroll
        for (int i = 0; i < 8; i++) {
            float wi = __shfl(wm, 8 * i + 4 * half + head, 64);   // w for edge 2i+half, this lane's head
            a0 += bf_lo(u[i].x) * wi;
            a1 += bf_hi(u[i].x) * wi;
            a2 += bf_lo(u[i].y) * wi;
            a3 += bf_hi(u[i].y) * wi;
            sw += wi;
        }
        ids = ids_n;
    }
    // combine edge-parity halves (lane and lane^32 hold same channels, complementary edges)
    a0 += __shfl_xor(a0, 32, 64);
    a1 += __shfl_xor(a1, 32, 64);
    a2 += __shfl_xor(a2, 32, 64);
    a3 += __shfl_xor(a3, 32, 64);
    sw += __shfl_xor(sw, 32, 64);
    float rs = 1.0f / (sw + 1e-16f);
    float4 bv = *(const float4*)(b1 + 4 * d5);
    float v0 = a0 * rs + bv.x;
    float v1 = a1 * rs + bv.y;
    float v2 = a2 * rs + bv.z;
    float v3 = a3 * rs + bv.w;
    v0 = (v0 > 0.f) ? v0 : (__expf(v0) - 1.0f);   // ELU
    v1 = (v1 > 0.f) ? v1 : (__expf(v1) - 1.0f);
    v2 = (v2 > 0.f) ? v2 : (__expf(v2) - 1.0f);
    v3 = (v3 > 0.f) ? v3 : (__expf(v3) - 1.0f);
    if (half == 0) {
        uint2 o;
        o.x = ((unsigned int)f2bf(v1) << 16) | (unsigned int)f2bf(v0);
        o.y = ((unsigned int)f2bf(v3) << 16) | (unsigned int)f2bf(v2);
        *(uint2*)(out1 + (size_t)node * 64 + 2 * d5) = o;
    }
}

// ================================================================ layer-2 gather: dword loads (2 rows/instr) + mean + log_softmax
__global__ __launch_bounds__(256) void k_gather2(const int* __restrict__ esrc,
                                                 const int* __restrict__ rowptr,
                                                 const unsigned int* __restrict__ h2,   // [N][32] dwords (bf16x2)
                                                 const float* __restrict__ as,          // [N][4]
                                                 const float* __restrict__ ad,          // [N][4]
                                                 const float* __restrict__ b2,
                                                 float* __restrict__ out) {
    int t = threadIdx.x;
    int node = blockIdx.x * 4 + (t >> 6);
    int lane = t & 63;
    int half = lane >> 5, d5 = lane & 31;
    int head = d5 >> 3;                  // channels 2*d5, 2*d5+1 -> head = d5>>3
    int j = lane >> 2, h4 = lane & 3;
    int beg = rowptr[node], end = rowptr[node + 1];
    float ad_w = ad[node * 4 + h4];
    float a0 = 0.f, a1 = 0.f, sw = 0.f;
    int ids = esrc[beg + j];
    for (int k = beg; k < end; k += 16) {
        float asv = as[ids * 4 + h4];
        unsigned int u[8];
        #pragma unroll
        for (int i = 0; i < 8; i++) {
            int sa = __shfl(ids, 8 * i, 64);
            int sb = __shfl(ids, 8 * i + 4, 64);
            int row = half ? sb : sa;
            u[i] = h2[(size_t)row * 32 + d5];
        }
        int ids_n = esrc[k + 16 + j];
        float wm = edge_w(asv, ad_w);
        if (k + j >= end) wm = 0.f;
        #pragma unroll
        for (int i = 0; i < 8; i++) {
            float wi = __shfl(wm, 8 * i + 4 * half + head, 64);
            a0 += bf_lo(u[i]) * wi;
            a1 += bf_hi(u[i]) * wi;
            sw += wi;
        }
        ids = ids_n;
    }
    a0 += __shfl_xor(a0, 32, 64);
    a1 += __shfl_xor(a1, 32, 64);
    sw += __shfl_xor(sw, 32, 64);
    float rs = 1.0f / (sw + 1e-16f);
    float v0 = a0 * rs, v1 = a1 * rs;
    // mean over 4 heads: lanes d5, d5^8, d5^16(+same half) hold same classes, different heads
    v0 += __shfl_xor(v0, 8, 64);  v0 += __shfl_xor(v0, 16, 64);
    v1 += __shfl_xor(v1, 8, 64);  v1 += __shfl_xor(v1, 16, 64);
    int c0 = 2 * (d5 & 7);
    v0 = v0 * 0.25f + b2[c0];
    v1 = v1 * 0.25f + b2[c0 + 1];
    // log_softmax over 16 classes: 8 lanes x 2 classes each
    float m = fmaxf(v0, v1);
    #pragma unroll
    for (int mask = 1; mask < 8; mask <<= 1) m = fmaxf(m, __shfl_xor(m, mask, 64));
    float se = __expf(v0 - m) + __expf(v1 - m);
    #pragma unroll
    for (int mask = 1; mask < 8; mask <<= 1) se += __shfl_xor(se, mask, 64);
    float ls = __logf(se);
    if (half == 0 && d5 < 8)
        *(float2*)(out + (size_t)node * 16 + c0) = make_float2((v0 - m) - ls, (v1 - m) - ls);
}

// ================================================================ host
extern "C" void kernel_launch(void* const* d_in, const int* in_sizes, int n_in,
                              void* d_out, int out_size, void* d_ws, size_t ws_size,
                              hipStream_t stream) {
    const float* x      = (const float*)d_in[0];
    const int*   ei     = (const int*)d_in[1];
    const float* Wemb   = (const float*)d_in[2];
    const float* bemb   = (const float*)d_in[3];
    const float* W1     = (const float*)d_in[4];
    const float* a_src1 = (const float*)d_in[5];
    const float* a_dst1 = (const float*)d_in[6];
    const float* b1     = (const float*)d_in[7];
    const float* W2     = (const float*)d_in[8];
    const float* a_src2 = (const float*)d_in[9];
    const float* a_dst2 = (const float*)d_in[10];
    const float* b2     = (const float*)d_in[11];
    float* out = (float*)d_out;

    char* ws = (char*)d_ws;
    size_t off = 0;
    auto alloc = [&](size_t bytes) { char* p = ws + off; off += (bytes + 255) & ~size_t(255); return p; };
    unsigned short* h1b   = (unsigned short*)alloc((size_t)N_NODES * 128 * 2);  // h2b [N][64] overlays front
    unsigned int*   out1b = (unsigned int*)alloc((size_t)N_NODES * 64 * 4);     // [N][64] bf16x2
    float*        h0    = (float*)alloc((size_t)N_NODES * HID * 4);
    int*          esrc  = (int*)alloc((size_t)N_EDGES * 4 + 256);               // +32 pad ints
    unsigned int* pairs = (unsigned int*)alloc((size_t)NBKT * CAP * 4);
    float* as     = (float*)alloc((size_t)N_NODES * 4 * 4);   // [N][4]
    float* ad     = (float*)alloc((size_t)N_NODES * 4 * 4);   // [N][4]
    int*   rowptr = (int*)alloc((size_t)(N_NODES + 1) * 4);
    int*   gcnt   = (int*)alloc((size_t)NBKT * 4);
    unsigned short* h2b = h1b;     // h1b dead after gather1

    const int GB = N_NODES / 4;    // 12500

    hipMemsetAsync(gcnt, 0, (size_t)NBKT * 4, stream);
    k_F1<<<NB64 + NBKT, 256, 0, stream>>>(x, Wemb, bemb, h0, ei, gcnt, pairs, esrc);
    k_F2<<<NB64 + NBKT, 256, 0, stream>>>(h0, W1, a_src1, a_dst1, h1b, as, ad,
                                          pairs, gcnt, rowptr, esrc);
    k_gather1<<<GB, 256, 0, stream>>>(esrc, rowptr, (const unsigned int*)h1b, as, ad, b1, out1b);
    k_h2f<<<NB64, 256, 0, stream>>>(out1b, W2, a_src2, a_dst2, h2b, as, ad);
    k_gather2<<<GB, 256, 0, stream>>>(esrc, rowptr, (const unsigned int*)h2b, as, ad, b2, out);
}